// Round 1
// baseline (26.116 us; speedup 1.0000x reference)
//
#include <hip/hip_runtime.h>

// Advection: out[b,i,j] = (s[b,min(i+1,H-1),j]-s[b,i,j])*v[b,i,j,0]
//                       + (s[b,i,min(j+1,W-1)]-s[b,i,j])*v[b,i,j,1]
// B=32, H=W=512, fp32. Memory-bound elementwise stencil.

#define H 512
#define W 512
#define PLANE (H * W)   // 262144

__global__ __launch_bounds__(256) void advect_kernel(
    const float* __restrict__ s,
    const float* __restrict__ v,
    float* __restrict__ out)
{
    const int t = blockIdx.x * blockDim.x + threadIdx.x;
    const int q = t << 2;                 // flat pixel index (4 pixels/thread)
    const int b   = q >> 18;              // / PLANE
    const int rem = q & (PLANE - 1);
    const int i   = rem >> 9;             // / W
    const int j   = rem & (W - 1);

    const float* srow   = s + (size_t)b * PLANE + (size_t)i * W;
    const int    idn    = (i + 1 < H) ? (i + 1) : (H - 1);
    const float* srowdn = s + (size_t)b * PLANE + (size_t)idn * W;

    const float4 s0 = *reinterpret_cast<const float4*>(srow + j);
    const float4 sd = *reinterpret_cast<const float4*>(srowdn + j);
    // right neighbor of pixel j+3 is j+4, clamped to W-1 (== s0.w when j+3==W-1)
    const float  s4 = (j + 4 < W) ? srow[j + 4] : s0.w;

    const float4 v01 = *reinterpret_cast<const float4*>(v + (size_t)q * 2);
    const float4 v23 = *reinterpret_cast<const float4*>(v + (size_t)q * 2 + 4);

    float4 o;
    o.x = (sd.x - s0.x) * v01.x + (s0.y - s0.x) * v01.y;
    o.y = (sd.y - s0.y) * v01.z + (s0.z - s0.y) * v01.w;
    o.z = (sd.z - s0.z) * v23.x + (s0.w - s0.z) * v23.y;
    o.w = (sd.w - s0.w) * v23.z + (s4   - s0.w) * v23.w;

    *reinterpret_cast<float4*>(out + q) = o;
}

extern "C" void kernel_launch(void* const* d_in, const int* in_sizes, int n_in,
                              void* d_out, int out_size, void* d_ws, size_t ws_size,
                              hipStream_t stream) {
    const float* s = (const float*)d_in[0];   // [32,512,512,1] f32
    const float* v = (const float*)d_in[1];   // [32,512,512,2] f32
    float* out = (float*)d_out;               // [32,512,512,1] f32

    const int n_pixels = 32 * PLANE;          // 8,388,608
    const int threads = n_pixels / 4;         // 2,097,152
    const int block = 256;
    const int grid = threads / block;         // 8192
    advect_kernel<<<grid, block, 0, stream>>>(s, v, out);
}